// Round 2
// baseline (2886.181 us; speedup 1.0000x reference)
//
#include <hip/hip_runtime.h>
#include <hip/hip_bf16.h>
#include <stdint.h>
#include <string.h>

// Problem constants
#define S_LEN 512
#define NBATCH 64
#define EDIM 128
#define HDIM 256
#define GDIM 1024  // 4*H

typedef __attribute__((ext_vector_type(8))) short short8;   // 8 bf16 (4 VGPRs) MFMA frag
typedef __attribute__((ext_vector_type(4))) short short4v;  // 4 bf16
typedef __attribute__((ext_vector_type(4))) float float4v;  // MFMA acc

// Workspace layout (bytes)
#define OFF_WHH 0u
#define SZ_WHH (64u * 8u * 64u * 16u)        // 512 KB: W_hh_f bf16 B-frags
#define OFF_WIH (OFF_WHH + SZ_WHH)
#define SZ_WIH (64u * 4u * 64u * 16u)        // 256 KB: W_ih_f bf16 B-frags
#define OFF_XG ((size_t)(OFF_WIH + SZ_WIH))
#define SZ_XG ((size_t)S_LEN * 4 * 64 * 64 * 8)  // 67 MB: xg_f bf16, fragment layout
#define OFF_HF (OFF_XG + SZ_XG)              // 64 KB: h_f final, fp32 [64][256]

__device__ __forceinline__ short f2bf(float f) {
    union { float f; unsigned u; } v;
    v.f = f;
    unsigned r = (v.u + 0x7fffu + ((v.u >> 16) & 1u)) >> 16;  // RNE
    return (short)r;
}
__device__ __forceinline__ float bf2f(short s) {
    union { unsigned u; float f; } v;
    v.u = ((unsigned)(unsigned short)s) << 16;
    return v.f;
}
__device__ __forceinline__ float sigm(float x) {
    float e = __expf(-x);                    // v_exp
    return __builtin_amdgcn_rcpf(1.0f + e);  // v_rcp
}
__device__ __forceinline__ float tanh_(float x) {
    float e = __expf(2.0f * x);              // overflow -> inf -> rcp 0 -> +1; underflow -> -1
    return 1.0f - 2.0f * __builtin_amdgcn_rcpf(e + 1.0f);
}

// ---------------------------------------------------------------------------
// Prep: fp32 weight [G,K] -> bf16 MFMA B-fragment layout.
// Fragment f = tile*nchunks + c; lane holds B[k = c*32+(lane>>4)*8 + j][n = lane&15]
// where gate row = tile*16 + n. Stored as 16B per (frag,lane).
// ---------------------------------------------------------------------------
__global__ __launch_bounds__(256) void prep_frags(const float* __restrict__ src,
                                                  char* __restrict__ dst,
                                                  int K, int nchunks, int nfrags) {
    int id = blockIdx.x * blockDim.x + threadIdx.x;
    int lane = id & 63;
    int f = id >> 6;
    if (f >= nfrags) return;
    int tile = f / nchunks;
    int c = f - tile * nchunks;
    int row = tile * 16 + (lane & 15);
    int k0 = c * 32 + ((lane >> 4) * 8);
    const float* s = src + (size_t)row * K + k0;
    short8 pack;
#pragma unroll
    for (int j = 0; j < 8; ++j) pack[j] = f2bf(s[j]);
    *(short8*)(dst + ((size_t)f * 64 + lane) * 16) = pack;
}

// ---------------------------------------------------------------------------
// Input projection: xg_f[t, b, gate] = x[t,b,:] @ W_ih_f^T + b_f, stored bf16 in
// MFMA C/D fragment layout: xg[((t*4+g)*64 + tile)*512 + lane*8] = 4 bf16.
// One block = 4 timesteps x 1 batch-group(16). 4 waves, wave w does N-tiles w*16..w*16+15.
// ---------------------------------------------------------------------------
__global__ __launch_bounds__(256) void input_proj(const int* __restrict__ seq,
                                                  const float* __restrict__ emb,
                                                  const char* __restrict__ wih_frags,
                                                  const float* __restrict__ bias,
                                                  char* __restrict__ xg) {
    __shared__ __align__(16) short lx[4][16][136];  // bf16 x-tiles, +8 pad
    int tid = threadIdx.x;
    int t0 = blockIdx.x * 4;
    int g = blockIdx.y;

    // stage x: 64 rows (4 t x 16 batch), 4 threads/row, 32 elems each
    {
        int row = tid >> 2;
        int tt = row >> 4, m = row & 15;
        int k0 = (tid & 3) * 32;
        int v = seq[(t0 + tt) * NBATCH + g * 16 + m];
        const float* src = emb + (size_t)v * EDIM + k0;
        bool zero = (v == 0);
#pragma unroll
        for (int u = 0; u < 32; u += 4) {
            float4v f = *(const float4v*)(src + u);
            short4v p;
#pragma unroll
            for (int e = 0; e < 4; ++e) p[e] = zero ? (short)0 : f2bf(f[e]);
            *(short4v*)&lx[tt][m][k0 + u] = p;
        }
    }
    __syncthreads();

    int lane = tid & 63, w = tid >> 6;
    int ln = lane & 15, q = lane >> 4;

    short8 Af[4][4];  // [t][kchunk]
#pragma unroll
    for (int tt = 0; tt < 4; ++tt)
#pragma unroll
        for (int c = 0; c < 4; ++c)
            Af[tt][c] = *(const short8*)&lx[tt][ln][c * 32 + q * 8];

    for (int nt = 0; nt < 16; ++nt) {
        int tile = w * 16 + nt;
        short8 Bf[4];
#pragma unroll
        for (int c = 0; c < 4; ++c)
            Bf[c] = *(const short8*)(wih_frags + (((size_t)tile * 4 + c) * 64 + lane) * 16);
        float b = bias[tile * 16 + ln];
#pragma unroll
        for (int tt = 0; tt < 4; ++tt) {
            float4v acc = {b, b, b, b};
#pragma unroll
            for (int c = 0; c < 4; ++c)
                acc = __builtin_amdgcn_mfma_f32_16x16x32_bf16(Af[tt][c], Bf[c], acc, 0, 0, 0);
            short4v p;
#pragma unroll
            for (int r = 0; r < 4; ++r) p[r] = f2bf(acc[r]);
            *(short4v*)(xg + ((((size_t)(t0 + tt) * 4 + g) * 64 + tile) * 64 + lane) * 8) = p;
        }
    }
}

// ---------------------------------------------------------------------------
// Forward LSTM scan, v2.
//   Grid = 4 blocks (batch groups of 16), 1024 threads = 16 waves (4/SIMD).
//   Wave w owns ONE hidden j-tile (jt = w) => gate tiles {w, 16+w, 32+w, 48+w}
//   (i,f,g,o). W_hh fragments for those 4 tiles live in registers (128 regs).
//   Step structure (ONE barrier/step):
//     - ds_read h A-frags from buf[p] (all waves read full h)
//     - issue xg prefetch for t+1 (consumed next step -> latency hidden)
//     - 4 independent MFMA chains, chunk-major (acc init from prefetched xg)
//     - activations + cell update (wave-local), ds_write h -> buf[p^1]
//     - __syncthreads, flip p
//   4 waves/SIMD lets MFMA issue overlap other waves' trans/VALU phase (m114).
// ---------------------------------------------------------------------------
__global__ __launch_bounds__(1024, 4) void lstm_scan(const char* __restrict__ whh_frags,
                                                     const char* __restrict__ xg,
                                                     float* __restrict__ hf_out) {
    __shared__ __align__(16) short hls[2][16][264];  // h bf16 [buf][batch][H], +8 pad
    int tid = threadIdx.x;
    int lane = tid & 63, w = tid >> 6;     // w = 0..15: hidden j-tile
    int ln = lane & 15, q = lane >> 4;
    int bg = blockIdx.x;                    // batch group

    int tiles[4];  // gate tiles: i, f, g, o at j-tile w
#pragma unroll
    for (int blk = 0; blk < 4; ++blk) tiles[blk] = 16 * blk + w;

    // W_hh fragments -> registers for the whole scan (4 tiles x 8 chunks = 128 regs)
    short8 Wfr[4][8];
#pragma unroll
    for (int ti = 0; ti < 4; ++ti)
#pragma unroll
        for (int c = 0; c < 8; ++c)
            Wfr[ti][c] = *(const short8*)(whh_frags +
                                          (((size_t)tiles[ti] * 8 + c) * 64 + lane) * 16);

    float cst[4];
#pragma unroll
    for (int r = 0; r < 4; ++r) cst[r] = 0.0f;

    // zero h buffer 0 (h0 = 0)
    {
        short* hp = &hls[0][0][0];
        for (int i = tid; i < 16 * 264; i += 1024) hp[i] = 0;
    }

    // per-lane invariant addresses
    const short* hrd = &hls[0][0][0];
    short* hwr = &hls[1][0][0];
    int ardoff = ln * 264 + q * 8;          // A-frag read offset (shorts), +c*32 per chunk
    int j = w * 16 + ln;                    // hidden column this lane's C-cols map to
    const char* xbase = xg + ((size_t)bg * 64) * 512 + (size_t)lane * 8;
    const size_t tstride = (size_t)4 * 64 * 512;  // bytes per timestep in xg

    // prefetch xg for t=0
    short4v xv[4], xvn[4];
#pragma unroll
    for (int ti = 0; ti < 4; ++ti)
        xv[ti] = *(const short4v*)(xbase + (size_t)tiles[ti] * 512);

    __syncthreads();

    for (int t = 0; t < S_LEN; ++t) {
        // h(t-1) A-fragments from current read buffer
        short8 Afr[8];
#pragma unroll
        for (int c = 0; c < 8; ++c)
            Afr[c] = *(const short8*)(hrd + ardoff + c * 32);

        // prefetch xg for t+1 (in flight across the whole step)
        if (t != S_LEN - 1) {
            const char* xp = xbase + (size_t)(t + 1) * tstride;
#pragma unroll
            for (int ti = 0; ti < 4; ++ti)
                xvn[ti] = *(const short4v*)(xp + (size_t)tiles[ti] * 512);
        }

        // acc init from prefetched xg (bf16 -> fp32 is a shift)
        float4v a[4];
#pragma unroll
        for (int ti = 0; ti < 4; ++ti)
#pragma unroll
            for (int r = 0; r < 4; ++r) a[ti][r] = bf2f(xv[ti][r]);

        // 4 independent MFMA chains, chunk-major (no acc-dependency stalls)
#pragma unroll
        for (int c = 0; c < 8; ++c)
#pragma unroll
            for (int ti = 0; ti < 4; ++ti)
                a[ti] = __builtin_amdgcn_mfma_f32_16x16x32_bf16(Afr[c], Wfr[ti][c], a[ti], 0, 0, 0);

        // activations: i,f,o sigmoid; g tanh
#pragma unroll
        for (int r = 0; r < 4; ++r) {
            a[0][r] = sigm(a[0][r]);
            a[1][r] = sigm(a[1][r]);
            a[2][r] = tanh_(a[2][r]);
            a[3][r] = sigm(a[3][r]);
        }

        // cell update + h write (wave-local)
#pragma unroll
        for (int r = 0; r < 4; ++r) {
            float cv = a[1][r] * cst[r] + a[0][r] * a[2][r];
            cst[r] = cv;
            float hv = a[3][r] * tanh_(cv);
            int b = q * 4 + r;
            hwr[b * 264 + j] = f2bf(hv);
            if (t == S_LEN - 1)
                hf_out[((size_t)bg * 16 + b) * HDIM + j] = hv;
        }

        // rotate prefetch regs and flip buffers; single barrier per step
#pragma unroll
        for (int ti = 0; ti < 4; ++ti) xv[ti] = xvn[ti];
        const short* tr = hrd; hrd = hwr; hwr = (short*)tr;
        __syncthreads();
    }
}

// ---------------------------------------------------------------------------
// Tail: backward cell at position S-1 (h0=c0=0 => W_hh_b unused) + output proj.
// One block per batch element; thread j handles hidden unit j.
// ---------------------------------------------------------------------------
__global__ __launch_bounds__(256) void tail_kernel(const int* __restrict__ seq,
                                                   const float* __restrict__ emb,
                                                   const float* __restrict__ wih_b,
                                                   const float* __restrict__ b_b,
                                                   const float* __restrict__ wout,
                                                   const float* __restrict__ b_out,
                                                   const float* __restrict__ hf,
                                                   float* __restrict__ out) {
    __shared__ float xs[EDIM];
    __shared__ float red[4];
    int b = blockIdx.x, tid = threadIdx.x;
    if (tid < EDIM) {
        int v = seq[(S_LEN - 1) * NBATCH + b];
        xs[tid] = (v == 0) ? 0.0f : emb[(size_t)v * EDIM + tid];
    }
    __syncthreads();

    int j = tid;  // 0..255 = hidden unit
    float si = b_b[j], sg = b_b[2 * HDIM + j], so = b_b[3 * HDIM + j];
    const float* wi = wih_b + (size_t)j * EDIM;
    const float* wg = wih_b + (size_t)(2 * HDIM + j) * EDIM;
    const float* wo = wih_b + (size_t)(3 * HDIM + j) * EDIM;
#pragma unroll 8
    for (int k = 0; k < EDIM; k += 4) {
        float4v x4 = *(const float4v*)&xs[k];
        float4v a = *(const float4v*)(wi + k);
        float4v c = *(const float4v*)(wg + k);
        float4v d = *(const float4v*)(wo + k);
#pragma unroll
        for (int e = 0; e < 4; ++e) {
            si += a[e] * x4[e];
            sg += c[e] * x4[e];
            so += d[e] * x4[e];
        }
    }
    float cc = sigm(si) * tanh_(sg);   // c = i*g   (f*c0 = 0)
    float hb = sigm(so) * tanh_(cc);   // h = o*tanh(c)
    float partial = hf[(size_t)b * HDIM + j] * wout[j] + hb * wout[HDIM + j];

    float val = partial;
#pragma unroll
    for (int off = 32; off > 0; off >>= 1) val += __shfl_down(val, off, 64);
    int lane = tid & 63, wv = tid >> 6;
    if (lane == 0) red[wv] = val;
    __syncthreads();
    if (tid == 0) out[b] = sigm(red[0] + red[1] + red[2] + red[3] + b_out[0]);
}

extern "C" void kernel_launch(void* const* d_in, const int* in_sizes, int n_in,
                              void* d_out, int out_size, void* d_ws, size_t ws_size,
                              hipStream_t stream) {
    const int* seq = (const int*)d_in[0];
    const float* emb = (const float*)d_in[1];
    const float* Wih_f = (const float*)d_in[2];
    const float* Whh_f = (const float*)d_in[3];
    const float* b_f = (const float*)d_in[4];
    const float* Wih_b = (const float*)d_in[5];
    // d_in[6] = W_hh_b: provably unused (backward scan's only needed output is its
    // step 0, where h0 = 0 so the recurrent term vanishes).
    const float* b_b = (const float*)d_in[7];
    const float* Wout = (const float*)d_in[8];
    const float* b_out = (const float*)d_in[9];
    float* out = (float*)d_out;
    char* ws = (char*)d_ws;

    // 1) weight fragments (bf16)
    prep_frags<<<dim3((64 * 8 * 64) / 256), 256, 0, stream>>>(Whh_f, ws + OFF_WHH, HDIM, 8, 64 * 8);
    prep_frags<<<dim3((64 * 4 * 64) / 256), 256, 0, stream>>>(Wih_f, ws + OFF_WIH, EDIM, 4, 64 * 4);
    // 2) forward input projections for all timesteps
    input_proj<<<dim3(S_LEN / 4, 4), 256, 0, stream>>>(seq, emb, ws + OFF_WIH, b_f, ws + OFF_XG);
    // 3) sequential forward scan (4 batch groups, 1 CU each, 16 waves)
    lstm_scan<<<dim3(4), 1024, 0, stream>>>(ws + OFF_WHH, ws + OFF_XG, (float*)(ws + OFF_HF));
    // 4) backward single cell + output projection
    tail_kernel<<<dim3(NBATCH), 256, 0, stream>>>(seq, emb, Wih_b, b_b, Wout, b_out,
                                                  (const float*)(ws + OFF_HF), out);
}

// Round 3
// 1020.816 us; speedup vs baseline: 2.8273x; 2.8273x over previous
//
#include <hip/hip_runtime.h>
#include <hip/hip_bf16.h>
#include <stdint.h>
#include <string.h>

// Problem constants
#define S_LEN 512
#define NBATCH 64
#define EDIM 128
#define HDIM 256
#define GDIM 1024  // 4*H

typedef __attribute__((ext_vector_type(8))) short short8;   // 8 bf16 (4 VGPRs) MFMA frag
typedef __attribute__((ext_vector_type(4))) short short4v;  // 4 bf16
typedef __attribute__((ext_vector_type(4))) float float4v;  // MFMA acc

// Workspace layout (bytes)
#define OFF_WHH8 0u
#define SZ_WHH8 (64u * 8u * 64u * 8u)        // 256 KB: W_hh_f fp8 A-frags
#define OFF_WIH (OFF_WHH8 + SZ_WHH8)
#define SZ_WIH (64u * 4u * 64u * 16u)        // 256 KB: W_ih_f bf16 frags
#define OFF_XG ((size_t)(OFF_WIH + SZ_WIH))
#define SZ_XG ((size_t)S_LEN * NBATCH * GDIM * 2)  // 67 MB: xg bf16 [t][b][1024]
#define OFF_HF (OFF_XG + SZ_XG)              // 64 KB: h_f final, fp32 [64][256]

__device__ __forceinline__ short f2bf(float f) {
    union { float f; unsigned u; } v;
    v.f = f;
    unsigned r = (v.u + 0x7fffu + ((v.u >> 16) & 1u)) >> 16;  // RNE
    return (short)r;
}
__device__ __forceinline__ float bf2f(short s) {
    union { unsigned u; float f; } v;
    v.u = ((unsigned)(unsigned short)s) << 16;
    return v.f;
}
__device__ __forceinline__ float sigm(float x) {
    float e = __expf(-x);                    // v_exp
    return __builtin_amdgcn_rcpf(1.0f + e);  // v_rcp
}
__device__ __forceinline__ float tanh_(float x) {
    float e = __expf(2.0f * x);              // overflow -> inf -> rcp 0 -> +1; underflow -> -1
    return 1.0f - 2.0f * __builtin_amdgcn_rcpf(e + 1.0f);
}

// ---------------------------------------------------------------------------
// Prep A: fp32 W_ih [G,128] -> bf16 MFMA fragments (8 B per lane pair-of-dwords
// layout identical to rounds 1-2; serves as A-operand: lane(ln,q) holds
// W[tile*16+ln][c*32+q*8+j], j=0..7).
// ---------------------------------------------------------------------------
__global__ __launch_bounds__(256) void prep_frags(const float* __restrict__ src,
                                                  char* __restrict__ dst,
                                                  int K, int nchunks, int nfrags) {
    int id = blockIdx.x * blockDim.x + threadIdx.x;
    int lane = id & 63;
    int f = id >> 6;
    if (f >= nfrags) return;
    int tile = f / nchunks;
    int c = f - tile * nchunks;
    int row = tile * 16 + (lane & 15);
    int k0 = c * 32 + ((lane >> 4) * 8);
    const float* s = src + (size_t)row * K + k0;
    short8 pack;
#pragma unroll
    for (int j = 0; j < 8; ++j) pack[j] = f2bf(s[j]);
    *(short8*)(dst + ((size_t)f * 64 + lane) * 16) = pack;
}

// ---------------------------------------------------------------------------
// Prep B: fp32 W_hh [1024,256] -> fp8 e4m3 A-fragments for mfma 16x16x32_fp8.
// Fragment f = tile*8 + c; lane(ln,q) holds 8 fp8 bytes
// W[tile*16+ln][c*32+q*8+j], j=0..7 (byte j = k offset j).
// ---------------------------------------------------------------------------
__global__ __launch_bounds__(256) void prep_whh_fp8(const float* __restrict__ src,
                                                    char* __restrict__ dst) {
    int id = blockIdx.x * blockDim.x + threadIdx.x;
    int lane = id & 63;
    int f = id >> 6;  // tile*8 + c, f < 512
    int tile = f >> 3, c = f & 7;
    int row = tile * 16 + (lane & 15);
    int k0 = c * 32 + ((lane >> 4) * 8);
    const float* s = src + (size_t)row * HDIM + k0;
    int d0 = __builtin_amdgcn_cvt_pk_fp8_f32(s[0], s[1], 0, false);
    d0 = __builtin_amdgcn_cvt_pk_fp8_f32(s[2], s[3], d0, true);
    int d1 = __builtin_amdgcn_cvt_pk_fp8_f32(s[4], s[5], 0, false);
    d1 = __builtin_amdgcn_cvt_pk_fp8_f32(s[6], s[7], d1, true);
    int* o = (int*)(dst + ((size_t)f * 64 + lane) * 8);
    o[0] = d0;
    o[1] = d1;
}

// ---------------------------------------------------------------------------
// Input projection (transposed): xg[t][b][j] = x[t,b,:] @ W_ih^T + b_f (bf16).
// MFMA with A = W_ih frag, B = x^T frag -> C[m=j][n=batch]: lane holds
// col=batch(ln), rows j = tile*16 + q*4 + r -> 4 consecutive j = one 8B store.
// Block = 4 timesteps x 16 batches; wave w covers j-tiles w*16..w*16+15.
// ---------------------------------------------------------------------------
__global__ __launch_bounds__(256) void input_proj(const int* __restrict__ seq,
                                                  const float* __restrict__ emb,
                                                  const char* __restrict__ wih_frags,
                                                  const float* __restrict__ bias,
                                                  char* __restrict__ xg) {
    __shared__ __align__(16) short lx[4][16][136];  // bf16 x-tiles, +8 pad
    int tid = threadIdx.x;
    int t0 = blockIdx.x * 4;
    int g = blockIdx.y;

    // stage x: 64 rows (4 t x 16 batch), 4 threads/row, 32 elems each
    {
        int row = tid >> 2;
        int tt = row >> 4, m = row & 15;
        int k0 = (tid & 3) * 32;
        int v = seq[(t0 + tt) * NBATCH + g * 16 + m];
        const float* src = emb + (size_t)v * EDIM + k0;
        bool zero = (v == 0);
#pragma unroll
        for (int u = 0; u < 32; u += 4) {
            float4v f = *(const float4v*)(src + u);
            short4v p;
#pragma unroll
            for (int e = 0; e < 4; ++e) p[e] = zero ? (short)0 : f2bf(f[e]);
            *(short4v*)&lx[tt][m][k0 + u] = p;
        }
    }
    __syncthreads();

    int lane = tid & 63, w = tid >> 6;
    int ln = lane & 15, q = lane >> 4;

    short8 Bx[4][4];  // x^T B-frags [t][kchunk]: lane holds x[batch=ln][k=c*32+q*8+j]
#pragma unroll
    for (int tt = 0; tt < 4; ++tt)
#pragma unroll
        for (int c = 0; c < 4; ++c)
            Bx[tt][c] = *(const short8*)&lx[tt][ln][c * 32 + q * 8];

    for (int nt = 0; nt < 16; ++nt) {
        int tile = w * 16 + nt;
        short8 Aw[4];
#pragma unroll
        for (int c = 0; c < 4; ++c)
            Aw[c] = *(const short8*)(wih_frags + (((size_t)tile * 4 + c) * 64 + lane) * 16);
        float4v b4 = *(const float4v*)(bias + tile * 16 + q * 4);
#pragma unroll
        for (int tt = 0; tt < 4; ++tt) {
            float4v acc = b4;
#pragma unroll
            for (int c = 0; c < 4; ++c)
                acc = __builtin_amdgcn_mfma_f32_16x16x32_bf16(Aw[c], Bx[tt][c], acc, 0, 0, 0);
            short4v p;
#pragma unroll
            for (int r = 0; r < 4; ++r) p[r] = f2bf(acc[r]);
            size_t off = ((size_t)(t0 + tt) * NBATCH + g * 16 + ln) * GDIM + tile * 16 + q * 4;
            *(short4v*)(xg + off * 2) = p;
        }
    }
}

// ---------------------------------------------------------------------------
// Forward LSTM scan, v3 (fp8, spill-free).
//   Grid = 4 blocks (batch groups of 16), 1024 threads = 16 waves.
//   Transposed GEMM: gates^T = W_hh @ h^T. A = W_hh fp8 frags (register-
//   resident: 4 tiles x 8 chunks x 2 dwords = 64 regs/lane -> whole W_hh fp8
//   = 256 KB = half the CU register file; total ~120 regs < 128 cap => NO
//   scratch spills, unlike rounds 1-2). B = h^T fp8 from LDS (ds_read_b64).
//   C[m=j][n=batch]: lane holds batch=ln, j = w*16+q*4+r -> h writeback is one
//   packed ds_write_b32 of 4 fp8. One barrier/step, double-buffered h.
// ---------------------------------------------------------------------------
__global__ __launch_bounds__(1024, 4) void lstm_scan(const char* __restrict__ whh8,
                                                     const char* __restrict__ xg,
                                                     float* __restrict__ hf_out) {
    __shared__ __align__(16) char hls[2][16][272];  // h fp8 [buf][batch][H], +16 pad
    int tid = threadIdx.x;
    int lane = tid & 63, w = tid >> 6;     // w = 0..15: hidden j-tile
    int ln = lane & 15, q = lane >> 4;
    int g = blockIdx.x;                     // batch group

    // W_hh fp8 A-frags -> registers for the whole scan (gate tiles i,f,g,o at j-tile w)
    long long Wfr[4][8];
#pragma unroll
    for (int blk = 0; blk < 4; ++blk) {
        int tile = 16 * blk + w;
#pragma unroll
        for (int c = 0; c < 8; ++c)
            Wfr[blk][c] = *(const long long*)(whh8 + (((size_t)tile * 8 + c) * 64 + lane) * 8);
    }

    float cst[4];
#pragma unroll
    for (int r = 0; r < 4; ++r) cst[r] = 0.0f;

    // zero both h buffers (h0 = 0; fp8 zero = 0x00)
    {
        int* hp = (int*)&hls[0][0][0];
        for (int i = tid; i < (2 * 16 * 272) / 4; i += 1024) hp[i] = 0;
    }

    const char* hrd = &hls[0][0][0];
    char* hwr = &hls[1][0][0];
    int hoff_rd = ln * 272 + q * 8;         // + c*32 per chunk
    int hoff_wr = ln * 272 + w * 16 + q * 4;

    // xg addressing: one lane offset + imm blk*512; SGPR base advances per step
    const char* xgp = xg + (((size_t)(g * 16 + ln) * GDIM + w * 16 + q * 4) * 2);
    const size_t tstep = (size_t)NBATCH * GDIM * 2;  // 131072 B

    short4v xv[4];
#pragma unroll
    for (int blk = 0; blk < 4; ++blk)
        xv[blk] = *(const short4v*)(xgp + blk * 512);

    __syncthreads();

    for (int t = 0; t < S_LEN; ++t) {
        // h(t-1) B-frags from read buffer
        long long Bh[8];
#pragma unroll
        for (int c = 0; c < 8; ++c)
            Bh[c] = *(const long long*)(hrd + hoff_rd + c * 32);

        // acc init from prefetched xg
        float4v a[4];
#pragma unroll
        for (int blk = 0; blk < 4; ++blk)
#pragma unroll
            for (int r = 0; r < 4; ++r) a[blk][r] = bf2f(xv[blk][r]);

        // prefetch next step's xg (in flight across the whole step)
        xgp += tstep;
        if (t != S_LEN - 1) {
#pragma unroll
            for (int blk = 0; blk < 4; ++blk)
                xv[blk] = *(const short4v*)(xgp + blk * 512);
        }

        // 4 independent MFMA chains, chunk-major
#pragma unroll
        for (int c = 0; c < 8; ++c)
#pragma unroll
            for (int blk = 0; blk < 4; ++blk)
                a[blk] = __builtin_amdgcn_mfma_f32_16x16x32_fp8_fp8(Wfr[blk][c], Bh[c], a[blk], 0, 0, 0);

        // activations: i,f,o sigmoid; g tanh
#pragma unroll
        for (int r = 0; r < 4; ++r) {
            a[0][r] = sigm(a[0][r]);
            a[1][r] = sigm(a[1][r]);
            a[2][r] = tanh_(a[2][r]);
            a[3][r] = sigm(a[3][r]);
        }

        // cell update; h -> a[3]
#pragma unroll
        for (int r = 0; r < 4; ++r) {
            float cv = a[1][r] * cst[r] + a[0][r] * a[2][r];
            cst[r] = cv;
            a[3][r] = a[3][r] * tanh_(cv);
        }

        // pack 4 h (consecutive j, one batch) to fp8 dword, write to other buffer
        int hp = __builtin_amdgcn_cvt_pk_fp8_f32(a[3][0], a[3][1], 0, false);
        hp = __builtin_amdgcn_cvt_pk_fp8_f32(a[3][2], a[3][3], hp, true);
        *(int*)(hwr + hoff_wr) = hp;

        if (t == S_LEN - 1) {
            float4v hv = {a[3][0], a[3][1], a[3][2], a[3][3]};
            *(float4v*)(hf_out + ((size_t)g * 16 + ln) * HDIM + w * 16 + q * 4) = hv;
        }

        const char* tr = hrd; hrd = hwr; hwr = (char*)tr;
        __syncthreads();
    }
}

// ---------------------------------------------------------------------------
// Tail: backward cell at position S-1 (h0=c0=0 => W_hh_b unused) + output proj.
// One block per batch element; thread j handles hidden unit j.
// ---------------------------------------------------------------------------
__global__ __launch_bounds__(256) void tail_kernel(const int* __restrict__ seq,
                                                   const float* __restrict__ emb,
                                                   const float* __restrict__ wih_b,
                                                   const float* __restrict__ b_b,
                                                   const float* __restrict__ wout,
                                                   const float* __restrict__ b_out,
                                                   const float* __restrict__ hf,
                                                   float* __restrict__ out) {
    __shared__ float xs[EDIM];
    __shared__ float red[4];
    int b = blockIdx.x, tid = threadIdx.x;
    if (tid < EDIM) {
        int v = seq[(S_LEN - 1) * NBATCH + b];
        xs[tid] = (v == 0) ? 0.0f : emb[(size_t)v * EDIM + tid];
    }
    __syncthreads();

    int j = tid;  // 0..255 = hidden unit
    float si = b_b[j], sg = b_b[2 * HDIM + j], so = b_b[3 * HDIM + j];
    const float* wi = wih_b + (size_t)j * EDIM;
    const float* wg = wih_b + (size_t)(2 * HDIM + j) * EDIM;
    const float* wo = wih_b + (size_t)(3 * HDIM + j) * EDIM;
#pragma unroll 8
    for (int k = 0; k < EDIM; k += 4) {
        float4v x4 = *(const float4v*)&xs[k];
        float4v a = *(const float4v*)(wi + k);
        float4v c = *(const float4v*)(wg + k);
        float4v d = *(const float4v*)(wo + k);
#pragma unroll
        for (int e = 0; e < 4; ++e) {
            si += a[e] * x4[e];
            sg += c[e] * x4[e];
            so += d[e] * x4[e];
        }
    }
    float cc = sigm(si) * tanh_(sg);   // c = i*g   (f*c0 = 0)
    float hb = sigm(so) * tanh_(cc);   // h = o*tanh(c)
    float partial = hf[(size_t)b * HDIM + j] * wout[j] + hb * wout[HDIM + j];

    float val = partial;
#pragma unroll
    for (int off = 32; off > 0; off >>= 1) val += __shfl_down(val, off, 64);
    int lane = tid & 63, wv = tid >> 6;
    if (lane == 0) red[wv] = val;
    __syncthreads();
    if (tid == 0) out[b] = sigm(red[0] + red[1] + red[2] + red[3] + b_out[0]);
}

extern "C" void kernel_launch(void* const* d_in, const int* in_sizes, int n_in,
                              void* d_out, int out_size, void* d_ws, size_t ws_size,
                              hipStream_t stream) {
    const int* seq = (const int*)d_in[0];
    const float* emb = (const float*)d_in[1];
    const float* Wih_f = (const float*)d_in[2];
    const float* Whh_f = (const float*)d_in[3];
    const float* b_f = (const float*)d_in[4];
    const float* Wih_b = (const float*)d_in[5];
    // d_in[6] = W_hh_b: provably unused (backward scan's only needed output is its
    // step 0, where h0 = 0 so the recurrent term vanishes).
    const float* b_b = (const float*)d_in[7];
    const float* Wout = (const float*)d_in[8];
    const float* b_out = (const float*)d_in[9];
    float* out = (float*)d_out;
    char* ws = (char*)d_ws;

    // 1) weight fragments: W_hh -> fp8 A-frags; W_ih -> bf16 frags
    prep_whh_fp8<<<dim3(128), 256, 0, stream>>>(Whh_f, ws + OFF_WHH8);
    prep_frags<<<dim3(64), 256, 0, stream>>>(Wih_f, ws + OFF_WIH, EDIM, 4, 64 * 4);
    // 2) forward input projections for all timesteps (xg bf16 [t][b][1024])
    input_proj<<<dim3(S_LEN / 4, 4), 256, 0, stream>>>(seq, emb, ws + OFF_WIH, b_f, ws + OFF_XG);
    // 3) sequential forward scan (4 batch groups, 1 CU each, 16 waves, fp8)
    lstm_scan<<<dim3(4), 1024, 0, stream>>>(ws + OFF_WHH8, ws + OFF_XG, (float*)(ws + OFF_HF));
    // 4) backward single cell + output projection
    tail_kernel<<<dim3(NBATCH), 256, 0, stream>>>(seq, emb, Wih_b, b_b, Wout, b_out,
                                                  (const float*)(ws + OFF_HF), out);
}